// Round 3
// baseline (511.377 us; speedup 1.0000x reference)
//
#include <hip/hip_runtime.h>
#include <hip/hip_bf16.h>

// MQA: B=2, S=2048, H=2048, NH=16, D=128
#define NB 2
#define NS 2048
#define NHID 2048
#define NHEAD 16
#define ND 128
#define NM (NB*NS)   // 4096

typedef __attribute__((ext_vector_type(8))) short s16x8;
typedef __attribute__((ext_vector_type(4))) float f32x4;

__device__ __forceinline__ short f2bf(float x) {
  unsigned u = __float_as_uint(x);
  u = (u + 0x7fffu + ((u >> 16) & 1u)) >> 16;
  return (short)u;
}

__device__ __forceinline__ int colmap(int wc, int ni) {
  return (ni < 2) ? (wc*32 + ni*16) : (64 + wc*32 + (ni-2)*16);
}

__device__ __forceinline__ void gload16(const short* g, short* l) {
  __builtin_amdgcn_global_load_lds(
      (const __attribute__((address_space(1))) void*)g,
      (__attribute__((address_space(3))) void*)l, 16, 0, 0);
}

// ---------------- conversions ----------------
__global__ __launch_bounds__(256) void cvt_f32_bf16(const float* __restrict__ src,
                                                    short* __restrict__ dst, int n4) {
  int i = blockIdx.x*256 + threadIdx.x;
  if (i >= n4) return;
  const float4 v = reinterpret_cast<const float4*>(src)[i];
  unsigned long long pk =
      (unsigned long long)(unsigned short)f2bf(v.x)
    | ((unsigned long long)(unsigned short)f2bf(v.y) << 16)
    | ((unsigned long long)(unsigned short)f2bf(v.z) << 32)
    | ((unsigned long long)(unsigned short)f2bf(v.w) << 48);
  reinterpret_cast<unsigned long long*>(dst)[i] = pk;
}

// src [K][N] fp32 -> dst [N][K] bf16
__global__ __launch_bounds__(256) void cvtT(const float* __restrict__ src,
                                            short* __restrict__ dst, int K, int N) {
  __shared__ float t[32][33];
  const int n0 = blockIdx.x*32, k0 = blockIdx.y*32;
  const int tx = threadIdx.x & 31, ty = threadIdx.x >> 5;
  #pragma unroll
  for (int i = 0; i < 4; ++i)
    t[ty + 8*i][tx] = src[(size_t)(k0 + ty + 8*i)*N + n0 + tx];
  __syncthreads();
  #pragma unroll
  for (int i = 0; i < 4; ++i)
    dst[(size_t)(n0 + ty + 8*i)*K + k0 + tx] = f2bf(t[tx][ty + 8*i]);
}

// Vb [4096][128] bf16 -> VbT [128][4096] bf16
__global__ __launch_bounds__(256) void trans_v(const short* __restrict__ src,
                                               short* __restrict__ dst) {
  __shared__ short t[32][40];
  const int c0 = blockIdx.x*32;   // d
  const int r0 = blockIdx.y*32;   // mrow
  const int tx = threadIdx.x & 31, ty = threadIdx.x >> 5;
  #pragma unroll
  for (int i = 0; i < 4; ++i)
    t[ty + 8*i][tx] = src[(size_t)(r0 + ty + 8*i)*128 + c0 + tx];
  __syncthreads();
  #pragma unroll
  for (int i = 0; i < 4; ++i)
    dst[(size_t)(c0 + ty + 8*i)*4096 + r0 + tx] = t[tx][ty + 8*i];
}

// ---------------- GEMM1: QKV projection + RoPE epilogue ----------------
__global__ __launch_bounds__(256) void gemm_qkv(
    const short* __restrict__ hsb, const short* __restrict__ WqT,
    const short* __restrict__ WkT, const short* __restrict__ WvT,
    const float* __restrict__ ropeC, const float* __restrict__ ropeS,
    short* __restrict__ Qb, short* __restrict__ Kb, short* __restrict__ Vb)
{
  const int tid = threadIdx.x;
  const int lane = tid & 63, wid = tid >> 6;
  const int wr = wid >> 1, wc = wid & 1;
  const int l15 = lane & 15, l4 = lane >> 4;
  const int m0 = blockIdx.x * 128;
  const int ny = blockIdx.y;
  const short* Bt = (ny < 16) ? (WqT + (size_t)ny*128*2048) : (ny == 16 ? WkT : WvT);

  __shared__ short Al[128][32];
  __shared__ short Bl[128][32];

  f32x4 acc[4][4];
  const f32x4 zf = {0.f,0.f,0.f,0.f};
  #pragma unroll
  for (int i=0;i<4;++i)
    #pragma unroll
    for (int j=0;j<4;++j) acc[i][j] = zf;

  const int srow = tid >> 2;
  const int scol = (tid & 3) * 8;
  const short* Ap0 = hsb + (size_t)(m0 + srow)*2048 + scol;
  const short* Ap1 = hsb + (size_t)(m0 + 64 + srow)*2048 + scol;
  const short* Bp0 = Bt + (size_t)srow*2048 + scol;
  const short* Bp1 = Bt + (size_t)(64 + srow)*2048 + scol;
  short* AL0 = &Al[0][0] + tid*8;
  short* AL1 = &Al[0][0] + 2048 + tid*8;
  short* BL0 = &Bl[0][0] + tid*8;
  short* BL1 = &Bl[0][0] + 2048 + tid*8;

  for (int kt = 0; kt < 64; ++kt) {
    const int k0 = kt * 32;
    __syncthreads();
    gload16(Ap0 + k0, AL0);
    gload16(Ap1 + k0, AL1);
    gload16(Bp0 + k0, BL0);
    gload16(Bp1 + k0, BL1);
    __syncthreads();
    s16x8 af[4], bfr[4];
    #pragma unroll
    for (int mi=0; mi<4; ++mi) af[mi] = *(const s16x8*)&Al[wr*64 + mi*16 + l15][l4*8];
    #pragma unroll
    for (int ni=0; ni<4; ++ni) bfr[ni] = *(const s16x8*)&Bl[colmap(wc,ni) + l15][l4*8];
    #pragma unroll
    for (int mi=0; mi<4; ++mi)
      #pragma unroll
      for (int ni=0; ni<4; ++ni)
        acc[mi][ni] = __builtin_amdgcn_mfma_f32_16x16x32_bf16(af[mi], bfr[ni], acc[mi][ni], 0,0,0);
  }

  const bool isQ = (ny < 16), isK = (ny == 16);
  #pragma unroll
  for (int mi=0; mi<4; ++mi) {
    #pragma unroll
    for (int r=0; r<4; ++r) {
      const int mrow = m0 + wr*64 + mi*16 + l4*4 + r;
      const int s = mrow & 2047;
      const int bb = mrow >> 11;
      if (!isQ && !isK) {
        #pragma unroll
        for (int ni=0; ni<4; ++ni) {
          const int d = colmap(wc,ni) + l15;
          Vb[(size_t)mrow*128 + d] = f2bf(acc[mi][ni][r]);
        }
      } else {
        #pragma unroll
        for (int ni=0; ni<2; ++ni) {
          const int d = colmap(wc,ni) + l15;
          const float c0 = ropeC[s*128 + d],      s0 = ropeS[s*128 + d];
          const float c1 = ropeC[s*128 + d + 64], s1 = ropeS[s*128 + d + 64];
          const float x0 = acc[mi][ni][r], x1 = acc[mi][ni+2][r];
          const float y0 = x0*c0 - x1*s0;
          const float y1 = x1*c1 + x0*s1;
          if (isK) {
            Kb[(size_t)mrow*128 + d]      = f2bf(y0);
            Kb[(size_t)mrow*128 + d + 64] = f2bf(y1);
          } else {
            const size_t base = ((size_t)(bb*16 + ny)*2048 + s)*128;
            Qb[base + d]      = f2bf(y0);
            Qb[base + d + 64] = f2bf(y1);
          }
        }
      }
    }
  }
}

// ---------------- flash attention: no staging, no barriers ----------------
__device__ __forceinline__ void attn_tile_proc(
    const s16x8 (&qf)[4], int qtile, int t, int wid, int l15, int l4,
    const short* __restrict__ Ktile, const short* __restrict__ Vtile,
    short (&Plw)[16][72],
    f32x4 (&o)[8], float (&m_run)[4], float (&l_run)[4])
{
  const float CEXP = 0.08838834764831845f * 1.44269504088896340f;
  const f32x4 zf = {0.f,0.f,0.f,0.f};
  f32x4 sc[4];
  #pragma unroll
  for (int n=0;n<4;++n) sc[n] = zf;
  // QK^T: K fragments straight from L2
  #pragma unroll
  for (int kk=0; kk<4; ++kk)
    #pragma unroll
    for (int n=0; n<4; ++n) {
      s16x8 kf = *(const s16x8*)(Ktile + (size_t)(n*16 + l15)*128 + kk*32 + l4*8);
      sc[n] = __builtin_amdgcn_mfma_f32_16x16x32_bf16(qf[kk], kf, sc[n], 0,0,0);
    }

  float p[4][4];
  const bool diag = (t == qtile);
  #pragma unroll
  for (int n=0;n<4;++n)
    #pragma unroll
    for (int r=0;r<4;++r) {
      float sv = sc[n][r];
      if (diag) {
        const int qg  = wid*16 + l4*4 + r;
        const int kvg = n*16 + l15;
        if (kvg > qg) sv = -1e30f;
      }
      p[n][r] = sv;
    }
  float pm[4];
  #pragma unroll
  for (int r=0;r<4;++r)
    pm[r] = fmaxf(fmaxf(p[0][r], p[1][r]), fmaxf(p[2][r], p[3][r]));
  #pragma unroll
  for (int d=1; d<16; d<<=1)
    #pragma unroll
    for (int r=0;r<4;++r) pm[r] = fmaxf(pm[r], __shfl_xor(pm[r], d));
  float alpha[4];
  #pragma unroll
  for (int r=0;r<4;++r) {
    const float mn = fmaxf(m_run[r], pm[r]);
    alpha[r] = exp2f((m_run[r] - mn) * CEXP);
    m_run[r] = mn;
  }
  #pragma unroll
  for (int n=0;n<4;++n)
    #pragma unroll
    for (int r=0;r<4;++r)
      p[n][r] = exp2f((p[n][r] - m_run[r]) * CEXP);
  float rs[4];
  #pragma unroll
  for (int r=0;r<4;++r) rs[r] = (p[0][r]+p[1][r])+(p[2][r]+p[3][r]);
  #pragma unroll
  for (int d=1; d<16; d<<=1)
    #pragma unroll
    for (int r=0;r<4;++r) rs[r] += __shfl_xor(rs[r], d);
  #pragma unroll
  for (int r=0;r<4;++r) l_run[r] = l_run[r]*alpha[r] + rs[r];
  #pragma unroll
  for (int i=0;i<8;++i)
    #pragma unroll
    for (int r=0;r<4;++r) o[i][r] *= alpha[r];

  // P -> per-wave LDS (wave-private, no barrier), re-read as A-fragments
  #pragma unroll
  for (int n=0;n<4;++n)
    #pragma unroll
    for (int r=0;r<4;++r)
      Plw[l4*4 + r][n*16 + l15] = f2bf(p[n][r]);

  s16x8 pa[2];
  #pragma unroll
  for (int kb=0; kb<2; ++kb) pa[kb] = *(const s16x8*)&Plw[l15][kb*32 + l4*8];
  // PV: V^T fragments straight from L2
  #pragma unroll
  for (int kb=0; kb<2; ++kb)
    #pragma unroll
    for (int d8=0; d8<8; ++d8) {
      s16x8 vf = *(const s16x8*)(Vtile + (size_t)(d8*16 + l15)*4096 + kb*32 + l4*8);
      o[d8] = __builtin_amdgcn_mfma_f32_16x16x32_bf16(pa[kb], vf, o[d8], 0,0,0);
    }
}

// grid flat 512: XCD-chunk swizzle; block owns q-tiles lo=pr, hi=31-pr (uniform 33 passes)
__global__ __launch_bounds__(256) void attn_fwd(
    const short* __restrict__ Qb, const short* __restrict__ Kb,
    const short* __restrict__ VbT, short* __restrict__ Ob)
{
  const int tid = threadIdx.x;
  const int lane = tid & 63, wid = tid >> 6;
  const int l15 = lane & 15, l4 = lane >> 4;
  const int bid = blockIdx.x;
  const int wg = (bid & 7)*64 + (bid >> 3);   // XCD x -> contiguous 64-block chunk
  const int pr = wg & 15, h = (wg >> 4) & 15, b = wg >> 8;
  const int lo = pr, hi = 31 - pr;

  __shared__ short Pl[4][16][72];

  s16x8 qfL[4], qfH[4];
  {
    const short* QpL = Qb + ((size_t)(b*16 + h)*2048 + lo*64 + wid*16 + l15)*128 + l4*8;
    const short* QpH = Qb + ((size_t)(b*16 + h)*2048 + hi*64 + wid*16 + l15)*128 + l4*8;
    #pragma unroll
    for (int kk=0; kk<4; ++kk) { qfL[kk] = *(const s16x8*)(QpL + kk*32);
                                 qfH[kk] = *(const s16x8*)(QpH + kk*32); }
  }

  float mL[4], lL[4], mH[4], lH[4];
  f32x4 oL[8], oH[8];
  const f32x4 zf = {0.f,0.f,0.f,0.f};
  #pragma unroll
  for (int r=0;r<4;++r){ mL[r]=-1e30f; lL[r]=0.f; mH[r]=-1e30f; lH[r]=0.f; }
  #pragma unroll
  for (int i=0;i<8;++i){ oL[i]=zf; oH[i]=zf; }

  for (int t=0; t<=hi; ++t) {
    const short* Ktile = Kb + ((size_t)b*2048 + t*64)*128;
    const short* Vtile = VbT + (size_t)b*2048 + t*64;
    attn_tile_proc(qfH, hi, t, wid, l15, l4, Ktile, Vtile, Pl[wid], oH, mH, lH);
    if (t <= lo)
      attn_tile_proc(qfL, lo, t, wid, l15, l4, Ktile, Vtile, Pl[wid], oL, mL, lL);
  }

  #pragma unroll
  for (int r=0;r<4;++r) {
    const float invL = 1.0f / lL[r];
    const float invH = 1.0f / lH[r];
    const size_t baseL = ((size_t)(b*2048) + lo*64 + wid*16 + l4*4 + r)*2048 + (size_t)h*128;
    const size_t baseH = ((size_t)(b*2048) + hi*64 + wid*16 + l4*4 + r)*2048 + (size_t)h*128;
    #pragma unroll
    for (int d8=0; d8<8; ++d8) {
      Ob[baseL + d8*16 + l15] = f2bf(oL[d8][r] * invL);
      Ob[baseH + d8*16 + l15] = f2bf(oH[d8][r] * invH);
    }
  }
}

// ---------------- GEMM2: O @ Wo -> fp32 out ----------------
__global__ __launch_bounds__(256) void gemm_out(
    const short* __restrict__ Ob, const short* __restrict__ WoT,
    float* __restrict__ out)
{
  const int tid = threadIdx.x;
  const int lane = tid & 63, wid = tid >> 6;
  const int wr = wid >> 1, wc = wid & 1;
  const int l15 = lane & 15, l4 = lane >> 4;
  const int m0 = blockIdx.x * 128;
  const int n0 = blockIdx.y * 128;

  __shared__ short Al[128][32];
  __shared__ short Bl[128][32];

  f32x4 acc[4][4];
  const f32x4 zf = {0.f,0.f,0.f,0.f};
  #pragma unroll
  for (int i=0;i<4;++i)
    #pragma unroll
    for (int j=0;j<4;++j) acc[i][j] = zf;

  const int srow = tid >> 2;
  const int scol = (tid & 3) * 8;
  const short* Ap0 = Ob + (size_t)(m0 + srow)*2048 + scol;
  const short* Ap1 = Ob + (size_t)(m0 + 64 + srow)*2048 + scol;
  const short* Bp0 = WoT + (size_t)(n0 + srow)*2048 + scol;
  const short* Bp1 = WoT + (size_t)(n0 + 64 + srow)*2048 + scol;
  short* AL0 = &Al[0][0] + tid*8;
  short* AL1 = &Al[0][0] + 2048 + tid*8;
  short* BL0 = &Bl[0][0] + tid*8;
  short* BL1 = &Bl[0][0] + 2048 + tid*8;

  for (int kt = 0; kt < 64; ++kt) {
    const int k0 = kt * 32;
    __syncthreads();
    gload16(Ap0 + k0, AL0);
    gload16(Ap1 + k0, AL1);
    gload16(Bp0 + k0, BL0);
    gload16(Bp1 + k0, BL1);
    __syncthreads();
    s16x8 af[4], bfr[4];
    #pragma unroll
    for (int mi=0; mi<4; ++mi) af[mi] = *(const s16x8*)&Al[wr*64 + mi*16 + l15][l4*8];
    #pragma unroll
    for (int ni=0; ni<4; ++ni) bfr[ni] = *(const s16x8*)&Bl[colmap(wc,ni) + l15][l4*8];
    #pragma unroll
    for (int mi=0; mi<4; ++mi)
      #pragma unroll
      for (int ni=0; ni<4; ++ni)
        acc[mi][ni] = __builtin_amdgcn_mfma_f32_16x16x32_bf16(af[mi], bfr[ni], acc[mi][ni], 0,0,0);
  }

  #pragma unroll
  for (int mi=0; mi<4; ++mi)
    #pragma unroll
    for (int r=0; r<4; ++r) {
      const int mrow = m0 + wr*64 + mi*16 + l4*4 + r;
      #pragma unroll
      for (int ni=0; ni<4; ++ni)
        out[(size_t)mrow*2048 + n0 + colmap(wc,ni) + l15] = acc[mi][ni][r];
    }
}

// ---------------- launch ----------------
extern "C" void kernel_launch(void* const* d_in, const int* in_sizes, int n_in,
                              void* d_out, int out_size, void* d_ws, size_t ws_size,
                              hipStream_t stream) {
  const float* hidden = (const float*)d_in[0];
  // d_in[1] attention_mask: exactly causal -> analytic
  const float* ropeC  = (const float*)d_in[2];
  const float* ropeS  = (const float*)d_in[3];
  const float* Wq     = (const float*)d_in[4];
  const float* Wk     = (const float*)d_in[5];
  const float* Wv     = (const float*)d_in[6];
  const float* Wo     = (const float*)d_in[7];
  float* out = (float*)d_out;
  char* ws = (char*)d_ws;

  short* hsb = (short*)(ws + 0);                 // 16,777,216
  short* WqT = (short*)(ws + 16777216);          //  8,388,608
  short* WkT = (short*)(ws + 25165824);          //    524,288
  short* WvT = (short*)(ws + 25690112);          //    524,288
  short* WoT = (short*)(ws + 26214400);          //  8,388,608
  short* Qb  = (short*)(ws + 34603008);          // 16,777,216
  short* Kb  = (short*)(ws + 51380224);          //  1,048,576
  short* Vb  = (short*)(ws + 52428800);          //  1,048,576
  short* VbT = (short*)(ws + 53477376);          //  1,048,576
  short* Ob  = hsb;                              // alias (hsb dead after gemm_qkv)

  cvt_f32_bf16<<<dim3((NM*NHID/4 + 255)/256), dim3(256), 0, stream>>>(hidden, hsb, NM*NHID/4);
  cvtT<<<dim3(64,64), dim3(256), 0, stream>>>(Wq, WqT, 2048, 2048);
  cvtT<<<dim3(4, 64), dim3(256), 0, stream>>>(Wk, WkT, 2048, 128);
  cvtT<<<dim3(4, 64), dim3(256), 0, stream>>>(Wv, WvT, 2048, 128);
  cvtT<<<dim3(64,64), dim3(256), 0, stream>>>(Wo, WoT, 2048, 2048);

  gemm_qkv<<<dim3(NM/128, 18), dim3(256), 0, stream>>>(hsb, WqT, WkT, WvT, ropeC, ropeS, Qb, Kb, Vb);
  trans_v<<<dim3(4, 128), dim3(256), 0, stream>>>(Vb, VbT);
  attn_fwd<<<dim3(512), dim3(256), 0, stream>>>(Qb, Kb, VbT, Ob);
  gemm_out<<<dim3(NM/128, 2048/128), dim3(256), 0, stream>>>(Ob, WoT, out);
}

// Round 4
// 412.005 us; speedup vs baseline: 1.2412x; 1.2412x over previous
//
#include <hip/hip_runtime.h>
#include <hip/hip_bf16.h>

// MQA: B=2, S=2048, H=2048, NH=16, D=128
#define NB 2
#define NS 2048
#define NHID 2048
#define NHEAD 16
#define ND 128
#define NM (NB*NS)   // 4096

typedef __attribute__((ext_vector_type(8))) short s16x8;
typedef __attribute__((ext_vector_type(4))) float f32x4;
typedef unsigned long long ull;

__device__ __forceinline__ short f2bf(float x) {
  unsigned u = __float_as_uint(x);
  u = (u + 0x7fffu + ((u >> 16) & 1u)) >> 16;
  return (short)u;
}

__device__ __forceinline__ int colmap(int wc, int ni) {
  return (ni < 2) ? (wc*32 + ni*16) : (64 + wc*32 + (ni-2)*16);
}

__device__ __forceinline__ void gload16(const short* g, short* l) {
  __builtin_amdgcn_global_load_lds(
      (const __attribute__((address_space(1))) void*)g,
      (__attribute__((address_space(3))) void*)l, 16, 0, 0);
}

// ---------------- conversions ----------------
__global__ __launch_bounds__(256) void cvt_f32_bf16(const float* __restrict__ src,
                                                    short* __restrict__ dst, int n4) {
  int i = blockIdx.x*256 + threadIdx.x;
  if (i >= n4) return;
  const float4 v = reinterpret_cast<const float4*>(src)[i];
  ull pk =
      (ull)(unsigned short)f2bf(v.x)
    | ((ull)(unsigned short)f2bf(v.y) << 16)
    | ((ull)(unsigned short)f2bf(v.z) << 32)
    | ((ull)(unsigned short)f2bf(v.w) << 48);
  reinterpret_cast<ull*>(dst)[i] = pk;
}

// src [K][N] fp32 -> dst [N][K] bf16
__global__ __launch_bounds__(256) void cvtT(const float* __restrict__ src,
                                            short* __restrict__ dst, int K, int N) {
  __shared__ float t[32][33];
  const int n0 = blockIdx.x*32, k0 = blockIdx.y*32;
  const int tx = threadIdx.x & 31, ty = threadIdx.x >> 5;
  #pragma unroll
  for (int i = 0; i < 4; ++i)
    t[ty + 8*i][tx] = src[(size_t)(k0 + ty + 8*i)*N + n0 + tx];
  __syncthreads();
  #pragma unroll
  for (int i = 0; i < 4; ++i)
    dst[(size_t)(n0 + ty + 8*i)*K + k0 + tx] = f2bf(t[tx][ty + 8*i]);
}

// Vb [4096][128] bf16 -> VbT [128][4096] bf16, XOR-swizzled: col s ^= (d&7)<<3
__global__ __launch_bounds__(256) void trans_v(const short* __restrict__ src,
                                               short* __restrict__ dst) {
  __shared__ short t[32][40];
  const int c0 = blockIdx.x*32;   // d
  const int r0 = blockIdx.y*32;   // mrow (s)
  const int tx = threadIdx.x & 31, ty = threadIdx.x >> 5;
  #pragma unroll
  for (int i = 0; i < 4; ++i)
    t[ty + 8*i][tx] = src[(size_t)(r0 + ty + 8*i)*128 + c0 + tx];
  __syncthreads();
  #pragma unroll
  for (int i = 0; i < 4; ++i) {
    const int d = c0 + ty + 8*i;
    dst[(size_t)d*4096 + ((r0 + tx) ^ ((d & 7) << 3))] = t[tx][ty + 8*i];
  }
}

// ---------------- GEMM1: QKV projection + RoPE epilogue ----------------
// K rows written XOR-swizzled: d ^= (s&7)<<3
__global__ __launch_bounds__(256) void gemm_qkv(
    const short* __restrict__ hsb, const short* __restrict__ WqT,
    const short* __restrict__ WkT, const short* __restrict__ WvT,
    const float* __restrict__ ropeC, const float* __restrict__ ropeS,
    short* __restrict__ Qb, short* __restrict__ Kb, short* __restrict__ Vb)
{
  const int tid = threadIdx.x;
  const int lane = tid & 63, wid = tid >> 6;
  const int wr = wid >> 1, wc = wid & 1;
  const int l15 = lane & 15, l4 = lane >> 4;
  const int m0 = blockIdx.x * 128;
  const int ny = blockIdx.y;
  const short* Bt = (ny < 16) ? (WqT + (size_t)ny*128*2048) : (ny == 16 ? WkT : WvT);

  __shared__ short Al[128][32];
  __shared__ short Bl[128][32];

  f32x4 acc[4][4];
  const f32x4 zf = {0.f,0.f,0.f,0.f};
  #pragma unroll
  for (int i=0;i<4;++i)
    #pragma unroll
    for (int j=0;j<4;++j) acc[i][j] = zf;

  const int srow = tid >> 2;
  const int scol = (tid & 3) * 8;
  const short* Ap0 = hsb + (size_t)(m0 + srow)*2048 + scol;
  const short* Ap1 = hsb + (size_t)(m0 + 64 + srow)*2048 + scol;
  const short* Bp0 = Bt + (size_t)srow*2048 + scol;
  const short* Bp1 = Bt + (size_t)(64 + srow)*2048 + scol;
  short* AL0 = &Al[0][0] + tid*8;
  short* AL1 = &Al[0][0] + 2048 + tid*8;
  short* BL0 = &Bl[0][0] + tid*8;
  short* BL1 = &Bl[0][0] + 2048 + tid*8;

  for (int kt = 0; kt < 64; ++kt) {
    const int k0 = kt * 32;
    __syncthreads();
    gload16(Ap0 + k0, AL0);
    gload16(Ap1 + k0, AL1);
    gload16(Bp0 + k0, BL0);
    gload16(Bp1 + k0, BL1);
    __syncthreads();
    s16x8 af[4], bfr[4];
    #pragma unroll
    for (int mi=0; mi<4; ++mi) af[mi] = *(const s16x8*)&Al[wr*64 + mi*16 + l15][l4*8];
    #pragma unroll
    for (int ni=0; ni<4; ++ni) bfr[ni] = *(const s16x8*)&Bl[colmap(wc,ni) + l15][l4*8];
    #pragma unroll
    for (int mi=0; mi<4; ++mi)
      #pragma unroll
      for (int ni=0; ni<4; ++ni)
        acc[mi][ni] = __builtin_amdgcn_mfma_f32_16x16x32_bf16(af[mi], bfr[ni], acc[mi][ni], 0,0,0);
  }

  const bool isQ = (ny < 16), isK = (ny == 16);
  #pragma unroll
  for (int mi=0; mi<4; ++mi) {
    #pragma unroll
    for (int r=0; r<4; ++r) {
      const int mrow = m0 + wr*64 + mi*16 + l4*4 + r;
      const int s = mrow & 2047;
      const int bb = mrow >> 11;
      if (!isQ && !isK) {
        #pragma unroll
        for (int ni=0; ni<4; ++ni) {
          const int d = colmap(wc,ni) + l15;
          Vb[(size_t)mrow*128 + d] = f2bf(acc[mi][ni][r]);
        }
      } else {
        #pragma unroll
        for (int ni=0; ni<2; ++ni) {
          const int d = colmap(wc,ni) + l15;      // [0,64)
          const float c0 = ropeC[s*128 + d],      s0 = ropeS[s*128 + d];
          const float c1 = ropeC[s*128 + d + 64], s1 = ropeS[s*128 + d + 64];
          const float x0 = acc[mi][ni][r], x1 = acc[mi][ni+2][r];
          const float y0 = x0*c0 - x1*s0;
          const float y1 = x1*c1 + x0*s1;
          if (isK) {
            const int dsw = d ^ ((s & 7) << 3);   // swizzled column (stays in [0,64))
            Kb[(size_t)mrow*128 + dsw]      = f2bf(y0);
            Kb[(size_t)mrow*128 + dsw + 64] = f2bf(y1);
          } else {
            const size_t base = ((size_t)(bb*16 + ny)*2048 + s)*128;
            Qb[base + d]      = f2bf(y0);
            Qb[base + d + 64] = f2bf(y1);
          }
        }
      }
    }
  }
}

// ---------------- flash attention: staged, dbuf, swapped-QK^T softmax ----------------
__device__ __forceinline__ void qkt_pair(const short* KL, const s16x8 (&qfH)[4],
                                         const s16x8 (&qfL)[4], f32x4 (&scH)[4],
                                         f32x4 (&scL)[4], int l15, int l4, int sw) {
  __builtin_amdgcn_s_setprio(1);
  #pragma unroll
  for (int kk=0; kk<4; ++kk)
    #pragma unroll
    for (int n=0; n<4; ++n) {
      s16x8 kf = *(const s16x8*)&KL[(n*16 + l15)*128 + ((kk*32 + l4*8) ^ sw)];
      scH[n] = __builtin_amdgcn_mfma_f32_16x16x32_bf16(kf, qfH[kk], scH[n], 0,0,0);
      scL[n] = __builtin_amdgcn_mfma_f32_16x16x32_bf16(kf, qfL[kk], scL[n], 0,0,0);
    }
  __builtin_amdgcn_s_setprio(0);
}

__device__ __forceinline__ void qkt_one(const short* KL, const s16x8 (&qf)[4],
                                        f32x4 (&sc)[4], int l15, int l4, int sw) {
  __builtin_amdgcn_s_setprio(1);
  #pragma unroll
  for (int kk=0; kk<4; ++kk)
    #pragma unroll
    for (int n=0; n<4; ++n) {
      s16x8 kf = *(const s16x8*)&KL[(n*16 + l15)*128 + ((kk*32 + l4*8) ^ sw)];
      sc[n] = __builtin_amdgcn_mfma_f32_16x16x32_bf16(kf, qf[kk], sc[n], 0,0,0);
    }
  __builtin_amdgcn_s_setprio(0);
}

// softmax in S^T domain: lane's q = l15, in-lane kv = n*16 + l4*4 + r
__device__ __forceinline__ void sm16(f32x4 (&sc)[4], bool diag, int wid, int l15, int l4,
                                     int sw, float &m_run, float &l_run, f32x4 (&o)[8],
                                     short* Pl) {
  const float CEXP = 0.08838834764831845f * 1.44269504088896340f;
  float p[4][4];
  #pragma unroll
  for (int n=0;n<4;++n)
    #pragma unroll
    for (int r=0;r<4;++r) {
      float sv = sc[n][r];
      if (diag && (n*16 + l4*4 + r > wid*16 + l15)) sv = -1e30f;
      p[n][r] = sv;
    }
  float pm = p[0][0];
  #pragma unroll
  for (int n=0;n<4;++n)
    #pragma unroll
    for (int r=0;r<4;++r) pm = fmaxf(pm, p[n][r]);
  pm = fmaxf(pm, __shfl_xor(pm, 16));
  pm = fmaxf(pm, __shfl_xor(pm, 32));
  const float mn = fmaxf(m_run, pm);
  const float al = exp2f((m_run - mn) * CEXP);
  m_run = mn;
  float rs = 0.f;
  #pragma unroll
  for (int n=0;n<4;++n)
    #pragma unroll
    for (int r=0;r<4;++r) { p[n][r] = exp2f((p[n][r] - mn) * CEXP); rs += p[n][r]; }
  rs += __shfl_xor(rs, 16);
  rs += __shfl_xor(rs, 32);
  l_run = l_run * al + rs;
  #pragma unroll
  for (int r=0;r<4;++r) {
    const float a = __shfl(al, l4*4 + r);
    #pragma unroll
    for (int i=0;i<8;++i) o[i][r] *= a;
  }
  #pragma unroll
  for (int n=0;n<4;++n) {
    ull w =
        (ull)(unsigned short)f2bf(p[n][0])
      | ((ull)(unsigned short)f2bf(p[n][1]) << 16)
      | ((ull)(unsigned short)f2bf(p[n][2]) << 32)
      | ((ull)(unsigned short)f2bf(p[n][3]) << 48);
    *(ull*)&Pl[l15*64 + ((n*16 + l4*4) ^ sw)] = w;
  }
}

__device__ __forceinline__ void pv_pair(const short* VL, const s16x8 (&paH)[2],
                                        const s16x8 (&paL)[2], f32x4 (&oH)[8],
                                        f32x4 (&oL)[8], int l15, int l4, int sw) {
  __builtin_amdgcn_s_setprio(1);
  #pragma unroll
  for (int kb=0; kb<2; ++kb)
    #pragma unroll
    for (int d8=0; d8<8; ++d8) {
      s16x8 vf = *(const s16x8*)&VL[(d8*16 + l15)*64 + ((kb*32 + l4*8) ^ sw)];
      oH[d8] = __builtin_amdgcn_mfma_f32_16x16x32_bf16(paH[kb], vf, oH[d8], 0,0,0);
      oL[d8] = __builtin_amdgcn_mfma_f32_16x16x32_bf16(paL[kb], vf, oL[d8], 0,0,0);
    }
  __builtin_amdgcn_s_setprio(0);
}

__device__ __forceinline__ void pv_one(const short* VL, const s16x8 (&pa)[2],
                                       f32x4 (&o)[8], int l15, int l4, int sw) {
  __builtin_amdgcn_s_setprio(1);
  #pragma unroll
  for (int kb=0; kb<2; ++kb)
    #pragma unroll
    for (int d8=0; d8<8; ++d8) {
      s16x8 vf = *(const s16x8*)&VL[(d8*16 + l15)*64 + ((kb*32 + l4*8) ^ sw)];
      o[d8] = __builtin_amdgcn_mfma_f32_16x16x32_bf16(pa[kb], vf, o[d8], 0,0,0);
    }
  __builtin_amdgcn_s_setprio(0);
}

// grid flat 512: XCD-chunk swizzle; block owns q-tiles lo=pr, hi=31-pr (33 passes)
__global__ __launch_bounds__(256) void attn_fwd(
    const short* __restrict__ Qb, const short* __restrict__ Kb,
    const short* __restrict__ VbT, short* __restrict__ Ob)
{
  const int tid = threadIdx.x;
  const int lane = tid & 63, wid = tid >> 6;
  const int l15 = lane & 15, l4 = lane >> 4;
  const int bid = blockIdx.x;
  const int wg = (bid & 7)*64 + (bid >> 3);
  const int pr = wg & 15, h = (wg >> 4) & 15, b = wg >> 8;
  const int lo = pr, hi = 31 - pr;
  const int sw = (l15 & 7) << 3;

  __shared__ short Kl[2][64*128];   // 32 KB
  __shared__ short Vt[2][128*64];   // 32 KB
  __shared__ short Pb[4][2][16*64]; // 16 KB
  short* PlH = &Pb[wid][0][0];
  short* PlL = &Pb[wid][1][0];

  s16x8 qfH[4], qfL[4];
  {
    const short* QpL = Qb + ((size_t)(b*16 + h)*2048 + lo*64 + wid*16 + l15)*128 + l4*8;
    const short* QpH = Qb + ((size_t)(b*16 + h)*2048 + hi*64 + wid*16 + l15)*128 + l4*8;
    #pragma unroll
    for (int kk=0; kk<4; ++kk) { qfL[kk] = *(const s16x8*)(QpL + kk*32);
                                 qfH[kk] = *(const s16x8*)(QpH + kk*32); }
  }

  float mH = -1e30f, lH = 0.f, mL = -1e30f, lL = 0.f;
  f32x4 oH[8], oL[8];
  const f32x4 zf = {0.f,0.f,0.f,0.f};
  #pragma unroll
  for (int i=0;i<8;++i){ oH[i]=zf; oL[i]=zf; }

  const short* Kg = Kb + (size_t)b*2048*128;
  const short* Vg = VbT + (size_t)b*2048;

  #define STAGE(bufi, tt) do {                                              \
    const int kv0_ = (tt)*64;                                               \
    _Pragma("unroll")                                                       \
    for (int rep=0; rep<4; ++rep) {                                         \
      const int c = tid + rep*256;                                          \
      gload16(Kg + (size_t)(kv0_ + (c>>4))*128 + (c&15)*8, &Kl[bufi][c*8]); \
    }                                                                       \
    _Pragma("unroll")                                                       \
    for (int rep=0; rep<4; ++rep) {                                         \
      const int c = tid + rep*256;                                          \
      gload16(Vg + (size_t)(c>>3)*4096 + kv0_ + (c&7)*8, &Vt[bufi][c*8]);   \
    }                                                                       \
  } while(0)

  STAGE(0, 0);
  __syncthreads();
  int buf = 0;
  int t = 0;

  // paired phase: t <= lo  (lo < hi always since lo<=15<16<=hi)
  for (; t <= lo; ++t) {
    STAGE(buf^1, t+1);
    const short* KL = &Kl[buf][0];
    const short* VL = &Vt[buf][0];
    f32x4 scH[4], scL[4];
    #pragma unroll
    for (int n=0;n<4;++n){ scH[n]=zf; scL[n]=zf; }
    qkt_pair(KL, qfH, qfL, scH, scL, l15, l4, sw);
    sm16(scH, false, wid, l15, l4, sw, mH, lH, oH, PlH);
    sm16(scL, (t == lo), wid, l15, l4, sw, mL, lL, oL, PlL);
    s16x8 paH[2], paL[2];
    #pragma unroll
    for (int kb=0; kb<2; ++kb) {
      paH[kb] = *(const s16x8*)&PlH[l15*64 + ((kb*32 + l4*8) ^ sw)];
      paL[kb] = *(const s16x8*)&PlL[l15*64 + ((kb*32 + l4*8) ^ sw)];
    }
    pv_pair(VL, paH, paL, oH, oL, l15, l4, sw);
    __syncthreads();
    buf ^= 1;
  }
  // H-only phase
  for (; t <= hi; ++t) {
    if (t < hi) STAGE(buf^1, t+1);
    const short* KL = &Kl[buf][0];
    const short* VL = &Vt[buf][0];
    f32x4 scH[4];
    #pragma unroll
    for (int n=0;n<4;++n) scH[n]=zf;
    qkt_one(KL, qfH, scH, l15, l4, sw);
    sm16(scH, (t == hi), wid, l15, l4, sw, mH, lH, oH, PlH);
    s16x8 paH[2];
    #pragma unroll
    for (int kb=0; kb<2; ++kb)
      paH[kb] = *(const s16x8*)&PlH[l15*64 + ((kb*32 + l4*8) ^ sw)];
    pv_one(VL, paH, oH, l15, l4, sw);
    __syncthreads();
    buf ^= 1;
  }
  #undef STAGE

  const float invH = 1.0f / lH;
  const float invL = 1.0f / lL;
  #pragma unroll
  for (int r=0;r<4;++r) {
    const float iH = __shfl(invH, l4*4 + r);
    const float iL = __shfl(invL, l4*4 + r);
    const size_t baseH = ((size_t)(b*2048) + hi*64 + wid*16 + l4*4 + r)*2048 + (size_t)h*128;
    const size_t baseL = ((size_t)(b*2048) + lo*64 + wid*16 + l4*4 + r)*2048 + (size_t)h*128;
    #pragma unroll
    for (int d8=0; d8<8; ++d8) {
      Ob[baseH + d8*16 + l15] = f2bf(oH[d8][r] * iH);
      Ob[baseL + d8*16 + l15] = f2bf(oL[d8][r] * iL);
    }
  }
}

// ---------------- GEMM2: O @ Wo -> fp32 out ----------------
__global__ __launch_bounds__(256) void gemm_out(
    const short* __restrict__ Ob, const short* __restrict__ WoT,
    float* __restrict__ out)
{
  const int tid = threadIdx.x;
  const int lane = tid & 63, wid = tid >> 6;
  const int wr = wid >> 1, wc = wid & 1;
  const int l15 = lane & 15, l4 = lane >> 4;
  const int m0 = blockIdx.x * 128;
  const int n0 = blockIdx.y * 128;

  __shared__ short Al[128][32];
  __shared__ short Bl[128][32];

  f32x4 acc[4][4];
  const f32x4 zf = {0.f,0.f,0.f,0.f};
  #pragma unroll
  for (int i=0;i<4;++i)
    #pragma unroll
    for (int j=0;j<4;++j) acc[i][j] = zf;

  const int srow = tid >> 2;
  const int scol = (tid & 3) * 8;
  const short* Ap0 = Ob + (size_t)(m0 + srow)*2048 + scol;
  const short* Ap1 = Ob + (size_t)(m0 + 64 + srow)*2048 + scol;
  const short* Bp0 = WoT + (size_t)(n0 + srow)*2048 + scol;
  const short* Bp1 = WoT + (size_t)(n0 + 64 + srow)*2048 + scol;
  short* AL0 = &Al[0][0] + tid*8;
  short* AL1 = &Al[0][0] + 2048 + tid*8;
  short* BL0 = &Bl[0][0] + tid*8;
  short* BL1 = &Bl[0][0] + 2048 + tid*8;

  for (int kt = 0; kt < 64; ++kt) {
    const int k0 = kt * 32;
    __syncthreads();
    gload16(Ap0 + k0, AL0);
    gload16(Ap1 + k0, AL1);
    gload16(Bp0 + k0, BL0);
    gload16(Bp1 + k0, BL1);
    __syncthreads();
    s16x8 af[4], bfr[4];
    #pragma unroll
    for (int mi=0; mi<4; ++mi) af[mi] = *(const s16x8*)&Al[wr*64 + mi*16 + l15][l4*8];
    #pragma unroll
    for (int ni=0; ni<4; ++ni) bfr[ni] = *(const s16x8*)&Bl[colmap(wc,ni) + l15][l4*8];
    #pragma unroll
    for (int mi=0; mi<4; ++mi)
      #pragma unroll
      for (int ni=0; ni<4; ++ni)
        acc[mi][ni] = __builtin_amdgcn_mfma_f32_16x16x32_bf16(af[mi], bfr[ni], acc[mi][ni], 0,0,0);
  }

  #pragma unroll
  for (int mi=0; mi<4; ++mi)
    #pragma unroll
    for (int r=0; r<4; ++r) {
      const int mrow = m0 + wr*64 + mi*16 + l4*4 + r;
      #pragma unroll
      for (int ni=0; ni<4; ++ni)
        out[(size_t)mrow*2048 + n0 + colmap(wc,ni) + l15] = acc[mi][ni][r];
    }
}

// ---------------- launch ----------------
extern "C" void kernel_launch(void* const* d_in, const int* in_sizes, int n_in,
                              void* d_out, int out_size, void* d_ws, size_t ws_size,
                              hipStream_t stream) {
  const float* hidden = (const float*)d_in[0];
  // d_in[1] attention_mask: exactly causal -> analytic
  const float* ropeC  = (const float*)d_in[2];
  const float* ropeS  = (const float*)d_in[3];
  const float* Wq     = (const float*)d_in[4];
  const float* Wk     = (const float*)d_in[5];
  const float* Wv     = (const float*)d_in[6];
  const float* Wo     = (const float*)d_in[7];
  float* out = (float*)d_out;
  char* ws = (char*)d_ws;

  short* hsb = (short*)(ws + 0);                 // 16,777,216
  short* WqT = (short*)(ws + 16777216);          //  8,388,608
  short* WkT = (short*)(ws + 25165824);          //    524,288
  short* WvT = (short*)(ws + 25690112);          //    524,288
  short* WoT = (short*)(ws + 26214400);          //  8,388,608
  short* Qb  = (short*)(ws + 34603008);          // 16,777,216
  short* Kb  = (short*)(ws + 51380224);          //  1,048,576
  short* Vb  = (short*)(ws + 52428800);          //  1,048,576
  short* VbT = (short*)(ws + 53477376);          //  1,048,576
  short* Ob  = hsb;                              // alias (hsb dead after gemm_qkv)

  cvt_f32_bf16<<<dim3((NM*NHID/4 + 255)/256), dim3(256), 0, stream>>>(hidden, hsb, NM*NHID/4);
  cvtT<<<dim3(64,64), dim3(256), 0, stream>>>(Wq, WqT, 2048, 2048);
  cvtT<<<dim3(4, 64), dim3(256), 0, stream>>>(Wk, WkT, 2048, 128);
  cvtT<<<dim3(4, 64), dim3(256), 0, stream>>>(Wv, WvT, 2048, 128);
  cvtT<<<dim3(64,64), dim3(256), 0, stream>>>(Wo, WoT, 2048, 2048);

  gemm_qkv<<<dim3(NM/128, 18), dim3(256), 0, stream>>>(hsb, WqT, WkT, WvT, ropeC, ropeS, Qb, Kb, Vb);
  trans_v<<<dim3(4, 128), dim3(256), 0, stream>>>(Vb, VbT);
  attn_fwd<<<dim3(512), dim3(256), 0, stream>>>(Qb, Kb, VbT, Ob);
  gemm_out<<<dim3(NM/128, 2048/128), dim3(256), 0, stream>>>(Ob, WoT, out);
}

// Round 5
// 409.956 us; speedup vs baseline: 1.2474x; 1.0050x over previous
//
#include <hip/hip_runtime.h>
#include <hip/hip_bf16.h>

// MQA: B=2, S=2048, H=2048, NH=16, D=128
#define NB 2
#define NS 2048
#define NHID 2048
#define NHEAD 16
#define ND 128
#define NM (NB*NS)   // 4096

typedef __attribute__((ext_vector_type(8))) short s16x8;
typedef __attribute__((ext_vector_type(4))) float f32x4;
typedef unsigned long long ull;

__device__ __forceinline__ short f2bf(float x) {
  unsigned u = __float_as_uint(x);
  u = (u + 0x7fffu + ((u >> 16) & 1u)) >> 16;
  return (short)u;
}

__device__ __forceinline__ float fexp2(float x) {
  float r; asm("v_exp_f32 %0, %1" : "=v"(r) : "v"(x)); return r;
}
__device__ __forceinline__ unsigned cvtpk(float lo, float hi) {
  unsigned r; asm("v_cvt_pk_bf16_f32 %0, %1, %2" : "=v"(r) : "v"(lo), "v"(hi)); return r;
}

__device__ __forceinline__ int colmap(int wc, int ni) {
  return (ni < 2) ? (wc*32 + ni*16) : (64 + wc*32 + (ni-2)*16);
}

__device__ __forceinline__ void gload16(const short* g, short* l) {
  __builtin_amdgcn_global_load_lds(
      (const __attribute__((address_space(1))) void*)g,
      (__attribute__((address_space(3))) void*)l, 16, 0, 0);
}

// ---------------- conversions ----------------
__global__ __launch_bounds__(256) void cvt_f32_bf16(const float* __restrict__ src,
                                                    short* __restrict__ dst, int n4) {
  int i = blockIdx.x*256 + threadIdx.x;
  if (i >= n4) return;
  const float4 v = reinterpret_cast<const float4*>(src)[i];
  ull pk =
      (ull)(unsigned)cvtpk(v.x, v.y)
    | ((ull)(unsigned)cvtpk(v.z, v.w) << 32);
  reinterpret_cast<ull*>(dst)[i] = pk;
}

// src [K][N] fp32 -> dst [N][K] bf16
__global__ __launch_bounds__(256) void cvtT(const float* __restrict__ src,
                                            short* __restrict__ dst, int K, int N) {
  __shared__ float t[32][33];
  const int n0 = blockIdx.x*32, k0 = blockIdx.y*32;
  const int tx = threadIdx.x & 31, ty = threadIdx.x >> 5;
  #pragma unroll
  for (int i = 0; i < 4; ++i)
    t[ty + 8*i][tx] = src[(size_t)(k0 + ty + 8*i)*N + n0 + tx];
  __syncthreads();
  #pragma unroll
  for (int i = 0; i < 4; ++i)
    dst[(size_t)(n0 + ty + 8*i)*K + k0 + tx] = f2bf(t[tx][ty + 8*i]);
}

// Vb [4096][128] bf16 -> VbT [128][4096] bf16, XOR-swizzled: col s ^= (d&7)<<3
__global__ __launch_bounds__(256) void trans_v(const short* __restrict__ src,
                                               short* __restrict__ dst) {
  __shared__ short t[32][40];
  const int c0 = blockIdx.x*32;   // d
  const int r0 = blockIdx.y*32;   // mrow (s)
  const int tx = threadIdx.x & 31, ty = threadIdx.x >> 5;
  #pragma unroll
  for (int i = 0; i < 4; ++i)
    t[ty + 8*i][tx] = src[(size_t)(r0 + ty + 8*i)*128 + c0 + tx];
  __syncthreads();
  #pragma unroll
  for (int i = 0; i < 4; ++i) {
    const int d = c0 + ty + 8*i;
    dst[(size_t)d*4096 + ((r0 + tx) ^ ((d & 7) << 3))] = t[tx][ty + 8*i];
  }
}

// ---------------- GEMM1: QKV projection + RoPE epilogue ----------------
// flat grid 576, XCD-chunk swizzle; K rows written XOR-swizzled: d ^= (s&7)<<3
__global__ __launch_bounds__(256) void gemm_qkv(
    const short* __restrict__ hsb, const short* __restrict__ WqT,
    const short* __restrict__ WkT, const short* __restrict__ WvT,
    const float* __restrict__ ropeC, const float* __restrict__ ropeS,
    short* __restrict__ Qb, short* __restrict__ Kb, short* __restrict__ Vb)
{
  const int tid = threadIdx.x;
  const int lane = tid & 63, wid = tid >> 6;
  const int wr = wid >> 1, wc = wid & 1;
  const int l15 = lane & 15, l4 = lane >> 4;
  const int bid = blockIdx.x;
  const int wg = (bid & 7) * 72 + (bid >> 3);   // 576 = 8*72, bijective
  const int m0 = (wg & 31) * 128;
  const int ny = wg >> 5;
  const short* Bt = (ny < 16) ? (WqT + (size_t)ny*128*2048) : (ny == 16 ? WkT : WvT);

  __shared__ short Al[128][32];
  __shared__ short Bl[128][32];

  f32x4 acc[4][4];
  const f32x4 zf = {0.f,0.f,0.f,0.f};
  #pragma unroll
  for (int i=0;i<4;++i)
    #pragma unroll
    for (int j=0;j<4;++j) acc[i][j] = zf;

  const int srow = tid >> 2;
  const int scol = (tid & 3) * 8;
  const short* Ap0 = hsb + (size_t)(m0 + srow)*2048 + scol;
  const short* Ap1 = hsb + (size_t)(m0 + 64 + srow)*2048 + scol;
  const short* Bp0 = Bt + (size_t)srow*2048 + scol;
  const short* Bp1 = Bt + (size_t)(64 + srow)*2048 + scol;
  short* AL0 = &Al[0][0] + tid*8;
  short* AL1 = &Al[0][0] + 2048 + tid*8;
  short* BL0 = &Bl[0][0] + tid*8;
  short* BL1 = &Bl[0][0] + 2048 + tid*8;

  for (int kt = 0; kt < 64; ++kt) {
    const int k0 = kt * 32;
    __syncthreads();
    gload16(Ap0 + k0, AL0);
    gload16(Ap1 + k0, AL1);
    gload16(Bp0 + k0, BL0);
    gload16(Bp1 + k0, BL1);
    __syncthreads();
    s16x8 af[4], bfr[4];
    #pragma unroll
    for (int mi=0; mi<4; ++mi) af[mi] = *(const s16x8*)&Al[wr*64 + mi*16 + l15][l4*8];
    #pragma unroll
    for (int ni=0; ni<4; ++ni) bfr[ni] = *(const s16x8*)&Bl[colmap(wc,ni) + l15][l4*8];
    #pragma unroll
    for (int mi=0; mi<4; ++mi)
      #pragma unroll
      for (int ni=0; ni<4; ++ni)
        acc[mi][ni] = __builtin_amdgcn_mfma_f32_16x16x32_bf16(af[mi], bfr[ni], acc[mi][ni], 0,0,0);
  }

  const bool isQ = (ny < 16), isK = (ny == 16);
  #pragma unroll
  for (int mi=0; mi<4; ++mi) {
    #pragma unroll
    for (int r=0; r<4; ++r) {
      const int mrow = m0 + wr*64 + mi*16 + l4*4 + r;
      const int s = mrow & 2047;
      const int bb = mrow >> 11;
      if (!isQ && !isK) {
        #pragma unroll
        for (int ni=0; ni<4; ++ni) {
          const int d = colmap(wc,ni) + l15;
          Vb[(size_t)mrow*128 + d] = f2bf(acc[mi][ni][r]);
        }
      } else {
        #pragma unroll
        for (int ni=0; ni<2; ++ni) {
          const int d = colmap(wc,ni) + l15;      // [0,64)
          const float c0 = ropeC[s*128 + d],      s0 = ropeS[s*128 + d];
          const float c1 = ropeC[s*128 + d + 64], s1 = ropeS[s*128 + d + 64];
          const float x0 = acc[mi][ni][r], x1 = acc[mi][ni+2][r];
          const float y0 = x0*c0 - x1*s0;
          const float y1 = x1*c1 + x0*s1;
          if (isK) {
            const int dsw = d ^ ((s & 7) << 3);   // swizzled column (stays in [0,64))
            Kb[(size_t)mrow*128 + dsw]      = f2bf(y0);
            Kb[(size_t)mrow*128 + dsw + 64] = f2bf(y1);
          } else {
            const size_t base = ((size_t)(bb*16 + ny)*2048 + s)*128;
            Qb[base + d]      = f2bf(y0);
            Qb[base + d + 64] = f2bf(y1);
          }
        }
      }
    }
  }
}

// ---------------- flash attention: staged, dbuf, swapped-QK^T softmax ----------------
__device__ __forceinline__ void qkt_pair(const short* KL, const s16x8 (&qfH)[4],
                                         const s16x8 (&qfL)[4], f32x4 (&scH)[4],
                                         f32x4 (&scL)[4], int l15, int l4, int sw) {
  __builtin_amdgcn_s_setprio(1);
  #pragma unroll
  for (int kk=0; kk<4; ++kk)
    #pragma unroll
    for (int n=0; n<4; ++n) {
      s16x8 kf = *(const s16x8*)&KL[(n*16 + l15)*128 + ((kk*32 + l4*8) ^ sw)];
      scH[n] = __builtin_amdgcn_mfma_f32_16x16x32_bf16(kf, qfH[kk], scH[n], 0,0,0);
      scL[n] = __builtin_amdgcn_mfma_f32_16x16x32_bf16(kf, qfL[kk], scL[n], 0,0,0);
    }
  __builtin_amdgcn_s_setprio(0);
}

__device__ __forceinline__ void qkt_one(const short* KL, const s16x8 (&qf)[4],
                                        f32x4 (&sc)[4], int l15, int l4, int sw) {
  __builtin_amdgcn_s_setprio(1);
  #pragma unroll
  for (int kk=0; kk<4; ++kk)
    #pragma unroll
    for (int n=0; n<4; ++n) {
      s16x8 kf = *(const s16x8*)&KL[(n*16 + l15)*128 + ((kk*32 + l4*8) ^ sw)];
      sc[n] = __builtin_amdgcn_mfma_f32_16x16x32_bf16(kf, qf[kk], sc[n], 0,0,0);
    }
  __builtin_amdgcn_s_setprio(0);
}

// softmax in S^T domain: lane's q = l15, in-lane kv = n*16 + l4*4 + r
// VALU-diet: raw v_exp, fma-folded arg, max3 tree, defer-max (THR=8), cvt_pk packing
__device__ __forceinline__ void sm16(f32x4 (&sc)[4], bool diag, int wid, int l15, int l4,
                                     int sw, float &m_run, float &l_run, f32x4 (&o)[8],
                                     short* Pl) {
  const float CEXP = 0.08838834764831845f * 1.44269504088896340f;
  float p[4][4];
  #pragma unroll
  for (int n=0;n<4;++n)
    #pragma unroll
    for (int r=0;r<4;++r) p[n][r] = sc[n][r];
  if (diag) {
    #pragma unroll
    for (int n=0;n<4;++n)
      #pragma unroll
      for (int r=0;r<4;++r)
        if (n*16 + l4*4 + r > wid*16 + l15) p[n][r] = -1e30f;
  }
  // max3-friendly tree
  float a0 = fmaxf(fmaxf(p[0][0], p[0][1]), p[0][2]);
  float a1 = fmaxf(fmaxf(p[0][3], p[1][0]), p[1][1]);
  float a2 = fmaxf(fmaxf(p[1][2], p[1][3]), p[2][0]);
  float a3 = fmaxf(fmaxf(p[2][1], p[2][2]), p[2][3]);
  float a4 = fmaxf(fmaxf(p[3][0], p[3][1]), p[3][2]);
  float b0 = fmaxf(fmaxf(a0, a1), a2);
  float b1 = fmaxf(fmaxf(a3, a4), p[3][3]);
  float pm = fmaxf(b0, b1);
  pm = fmaxf(pm, __shfl_xor(pm, 16));
  pm = fmaxf(pm, __shfl_xor(pm, 32));

  // defer-max: skip rescale while max drifts < 8 (P bounded by 2^(8*CEXP) ~ 2.03)
  if (!__all(pm <= m_run + 8.0f)) {
    const float mn = fmaxf(m_run, pm);
    const float al = fexp2((m_run - mn) * CEXP);
    m_run = mn;
    l_run *= al;
    #pragma unroll
    for (int r=0;r<4;++r) {
      const float a = __shfl(al, l4*4 + r);
      #pragma unroll
      for (int i=0;i<8;++i) o[i][r] *= a;
    }
  }
  const float mC = m_run * CEXP;
  #pragma unroll
  for (int n=0;n<4;++n)
    #pragma unroll
    for (int r=0;r<4;++r)
      p[n][r] = fexp2(__builtin_fmaf(p[n][r], CEXP, -mC));
  // pack + write P early; ds latency hides under the row-sum below
  #pragma unroll
  for (int n=0;n<4;++n) {
    ull w = (ull)(unsigned)cvtpk(p[n][0], p[n][1])
          | ((ull)(unsigned)cvtpk(p[n][2], p[n][3]) << 32);
    *(ull*)&Pl[l15*64 + ((n*16 + l4*4) ^ sw)] = w;
  }
  float rs = 0.f;
  #pragma unroll
  for (int n=0;n<4;++n)
    #pragma unroll
    for (int r=0;r<4;++r) rs += p[n][r];
  rs += __shfl_xor(rs, 16);
  rs += __shfl_xor(rs, 32);
  l_run += rs;
}

__device__ __forceinline__ void pv_pair(const short* VL, const s16x8 (&paH)[2],
                                        const s16x8 (&paL)[2], f32x4 (&oH)[8],
                                        f32x4 (&oL)[8], int l15, int l4, int sw) {
  __builtin_amdgcn_s_setprio(1);
  #pragma unroll
  for (int kb=0; kb<2; ++kb)
    #pragma unroll
    for (int d8=0; d8<8; ++d8) {
      s16x8 vf = *(const s16x8*)&VL[(d8*16 + l15)*64 + ((kb*32 + l4*8) ^ sw)];
      oH[d8] = __builtin_amdgcn_mfma_f32_16x16x32_bf16(paH[kb], vf, oH[d8], 0,0,0);
      oL[d8] = __builtin_amdgcn_mfma_f32_16x16x32_bf16(paL[kb], vf, oL[d8], 0,0,0);
    }
  __builtin_amdgcn_s_setprio(0);
}

__device__ __forceinline__ void pv_one(const short* VL, const s16x8 (&pa)[2],
                                       f32x4 (&o)[8], int l15, int l4, int sw) {
  __builtin_amdgcn_s_setprio(1);
  #pragma unroll
  for (int kb=0; kb<2; ++kb)
    #pragma unroll
    for (int d8=0; d8<8; ++d8) {
      s16x8 vf = *(const s16x8*)&VL[(d8*16 + l15)*64 + ((kb*32 + l4*8) ^ sw)];
      o[d8] = __builtin_amdgcn_mfma_f32_16x16x32_bf16(pa[kb], vf, o[d8], 0,0,0);
    }
  __builtin_amdgcn_s_setprio(0);
}

// grid flat 512: XCD-chunk swizzle; block owns q-tiles lo=pr, hi=31-pr (33 passes)
__global__ __launch_bounds__(256) void attn_fwd(
    const short* __restrict__ Qb, const short* __restrict__ Kb,
    const short* __restrict__ VbT, short* __restrict__ Ob)
{
  const int tid = threadIdx.x;
  const int lane = tid & 63, wid = tid >> 6;
  const int l15 = lane & 15, l4 = lane >> 4;
  const int bid = blockIdx.x;
  const int wg = (bid & 7)*64 + (bid >> 3);
  const int pr = wg & 15, h = (wg >> 4) & 15, b = wg >> 8;
  const int lo = pr, hi = 31 - pr;
  const int sw = (l15 & 7) << 3;

  __shared__ short Kl[2][64*128];   // 32 KB
  __shared__ short Vt[2][128*64];   // 32 KB
  __shared__ short Pb[4][2][16*64]; // 16 KB
  short* PlH = &Pb[wid][0][0];
  short* PlL = &Pb[wid][1][0];

  s16x8 qfH[4], qfL[4];
  {
    const short* QpL = Qb + ((size_t)(b*16 + h)*2048 + lo*64 + wid*16 + l15)*128 + l4*8;
    const short* QpH = Qb + ((size_t)(b*16 + h)*2048 + hi*64 + wid*16 + l15)*128 + l4*8;
    #pragma unroll
    for (int kk=0; kk<4; ++kk) { qfL[kk] = *(const s16x8*)(QpL + kk*32);
                                 qfH[kk] = *(const s16x8*)(QpH + kk*32); }
  }

  float mH = -1e30f, lH = 0.f, mL = -1e30f, lL = 0.f;
  f32x4 oH[8], oL[8];
  const f32x4 zf = {0.f,0.f,0.f,0.f};
  #pragma unroll
  for (int i=0;i<8;++i){ oH[i]=zf; oL[i]=zf; }

  const short* Kg = Kb + (size_t)b*2048*128;
  const short* Vg = VbT + (size_t)b*2048;

  #define STAGE(bufi, tt) do {                                              \
    const int kv0_ = (tt)*64;                                               \
    _Pragma("unroll")                                                       \
    for (int rep=0; rep<4; ++rep) {                                         \
      const int c = tid + rep*256;                                          \
      gload16(Kg + (size_t)(kv0_ + (c>>4))*128 + (c&15)*8, &Kl[bufi][c*8]); \
    }                                                                       \
    _Pragma("unroll")                                                       \
    for (int rep=0; rep<4; ++rep) {                                         \
      const int c = tid + rep*256;                                          \
      gload16(Vg + (size_t)(c>>3)*4096 + kv0_ + (c&7)*8, &Vt[bufi][c*8]);   \
    }                                                                       \
  } while(0)

  STAGE(0, 0);
  __syncthreads();
  int buf = 0;
  int t = 0;

  // paired phase: t <= lo  (lo < hi always since lo<=15<16<=hi)
  for (; t <= lo; ++t) {
    STAGE(buf^1, t+1);
    const short* KL = &Kl[buf][0];
    const short* VL = &Vt[buf][0];
    f32x4 scH[4], scL[4];
    #pragma unroll
    for (int n=0;n<4;++n){ scH[n]=zf; scL[n]=zf; }
    qkt_pair(KL, qfH, qfL, scH, scL, l15, l4, sw);
    sm16(scH, false, wid, l15, l4, sw, mH, lH, oH, PlH);
    sm16(scL, (t == lo), wid, l15, l4, sw, mL, lL, oL, PlL);
    s16x8 paH[2], paL[2];
    #pragma unroll
    for (int kb=0; kb<2; ++kb) {
      paH[kb] = *(const s16x8*)&PlH[l15*64 + ((kb*32 + l4*8) ^ sw)];
      paL[kb] = *(const s16x8*)&PlL[l15*64 + ((kb*32 + l4*8) ^ sw)];
    }
    pv_pair(VL, paH, paL, oH, oL, l15, l4, sw);
    __syncthreads();
    buf ^= 1;
  }
  // H-only phase
  for (; t <= hi; ++t) {
    if (t < hi) STAGE(buf^1, t+1);
    const short* KL = &Kl[buf][0];
    const short* VL = &Vt[buf][0];
    f32x4 scH[4];
    #pragma unroll
    for (int n=0;n<4;++n) scH[n]=zf;
    qkt_one(KL, qfH, scH, l15, l4, sw);
    sm16(scH, (t == hi), wid, l15, l4, sw, mH, lH, oH, PlH);
    s16x8 paH[2];
    #pragma unroll
    for (int kb=0; kb<2; ++kb)
      paH[kb] = *(const s16x8*)&PlH[l15*64 + ((kb*32 + l4*8) ^ sw)];
    pv_one(VL, paH, oH, l15, l4, sw);
    __syncthreads();
    buf ^= 1;
  }
  #undef STAGE

  const float invH = 1.0f / lH;
  const float invL = 1.0f / lL;
  #pragma unroll
  for (int r=0;r<4;++r) {
    const float iH = __shfl(invH, l4*4 + r);
    const float iL = __shfl(invL, l4*4 + r);
    const size_t baseH = ((size_t)(b*2048) + hi*64 + wid*16 + l4*4 + r)*2048 + (size_t)h*128;
    const size_t baseL = ((size_t)(b*2048) + lo*64 + wid*16 + l4*4 + r)*2048 + (size_t)h*128;
    #pragma unroll
    for (int d8=0; d8<8; ++d8) {
      Ob[baseH + d8*16 + l15] = f2bf(oH[d8][r] * iH);
      Ob[baseL + d8*16 + l15] = f2bf(oL[d8][r] * iL);
    }
  }
}

// ---------------- GEMM2: O @ Wo -> fp32 out ----------------
__global__ __launch_bounds__(256) void gemm_out(
    const short* __restrict__ Ob, const short* __restrict__ WoT,
    float* __restrict__ out)
{
  const int tid = threadIdx.x;
  const int lane = tid & 63, wid = tid >> 6;
  const int wr = wid >> 1, wc = wid & 1;
  const int l15 = lane & 15, l4 = lane >> 4;
  const int bid = blockIdx.x;
  const int wg = (bid & 7) * 64 + (bid >> 3);   // 512 = 8*64, bijective
  const int m0 = (wg & 31) * 128;
  const int n0 = (wg >> 5) * 128;

  __shared__ short Al[128][32];
  __shared__ short Bl[128][32];

  f32x4 acc[4][4];
  const f32x4 zf = {0.f,0.f,0.f,0.f};
  #pragma unroll
  for (int i=0;i<4;++i)
    #pragma unroll
    for (int j=0;j<4;++j) acc[i][j] = zf;

  const int srow = tid >> 2;
  const int scol = (tid & 3) * 8;
  const short* Ap0 = Ob + (size_t)(m0 + srow)*2048 + scol;
  const short* Ap1 = Ob + (size_t)(m0 + 64 + srow)*2048 + scol;
  const short* Bp0 = WoT + (size_t)(n0 + srow)*2048 + scol;
  const short* Bp1 = WoT + (size_t)(n0 + 64 + srow)*2048 + scol;
  short* AL0 = &Al[0][0] + tid*8;
  short* AL1 = &Al[0][0] + 2048 + tid*8;
  short* BL0 = &Bl[0][0] + tid*8;
  short* BL1 = &Bl[0][0] + 2048 + tid*8;

  for (int kt = 0; kt < 64; ++kt) {
    const int k0 = kt * 32;
    __syncthreads();
    gload16(Ap0 + k0, AL0);
    gload16(Ap1 + k0, AL1);
    gload16(Bp0 + k0, BL0);
    gload16(Bp1 + k0, BL1);
    __syncthreads();
    s16x8 af[4], bfr[4];
    #pragma unroll
    for (int mi=0; mi<4; ++mi) af[mi] = *(const s16x8*)&Al[wr*64 + mi*16 + l15][l4*8];
    #pragma unroll
    for (int ni=0; ni<4; ++ni) bfr[ni] = *(const s16x8*)&Bl[colmap(wc,ni) + l15][l4*8];
    #pragma unroll
    for (int mi=0; mi<4; ++mi)
      #pragma unroll
      for (int ni=0; ni<4; ++ni)
        acc[mi][ni] = __builtin_amdgcn_mfma_f32_16x16x32_bf16(af[mi], bfr[ni], acc[mi][ni], 0,0,0);
  }

  #pragma unroll
  for (int mi=0; mi<4; ++mi)
    #pragma unroll
    for (int r=0; r<4; ++r) {
      const int mrow = m0 + wr*64 + mi*16 + l4*4 + r;
      #pragma unroll
      for (int ni=0; ni<4; ++ni)
        out[(size_t)mrow*2048 + n0 + colmap(wc,ni) + l15] = acc[mi][ni][r];
    }
}

// ---------------- launch ----------------
extern "C" void kernel_launch(void* const* d_in, const int* in_sizes, int n_in,
                              void* d_out, int out_size, void* d_ws, size_t ws_size,
                              hipStream_t stream) {
  const float* hidden = (const float*)d_in[0];
  // d_in[1] attention_mask: exactly causal -> analytic
  const float* ropeC  = (const float*)d_in[2];
  const float* ropeS  = (const float*)d_in[3];
  const float* Wq     = (const float*)d_in[4];
  const float* Wk     = (const float*)d_in[5];
  const float* Wv     = (const float*)d_in[6];
  const float* Wo     = (const float*)d_in[7];
  float* out = (float*)d_out;
  char* ws = (char*)d_ws;

  short* hsb = (short*)(ws + 0);                 // 16,777,216
  short* WqT = (short*)(ws + 16777216);          //  8,388,608
  short* WkT = (short*)(ws + 25165824);          //    524,288
  short* WvT = (short*)(ws + 25690112);          //    524,288
  short* WoT = (short*)(ws + 26214400);          //  8,388,608
  short* Qb  = (short*)(ws + 34603008);          // 16,777,216
  short* Kb  = (short*)(ws + 51380224);          //  1,048,576
  short* Vb  = (short*)(ws + 52428800);          //  1,048,576
  short* VbT = (short*)(ws + 53477376);          //  1,048,576
  short* Ob  = hsb;                              // alias (hsb dead after gemm_qkv)

  cvt_f32_bf16<<<dim3((NM*NHID/4 + 255)/256), dim3(256), 0, stream>>>(hidden, hsb, NM*NHID/4);
  cvtT<<<dim3(64,64), dim3(256), 0, stream>>>(Wq, WqT, 2048, 2048);
  cvtT<<<dim3(4, 64), dim3(256), 0, stream>>>(Wk, WkT, 2048, 128);
  cvtT<<<dim3(4, 64), dim3(256), 0, stream>>>(Wv, WvT, 2048, 128);
  cvtT<<<dim3(64,64), dim3(256), 0, stream>>>(Wo, WoT, 2048, 2048);

  gemm_qkv<<<dim3(576), dim3(256), 0, stream>>>(hsb, WqT, WkT, WvT, ropeC, ropeS, Qb, Kb, Vb);
  trans_v<<<dim3(4, 128), dim3(256), 0, stream>>>(Vb, VbT);
  attn_fwd<<<dim3(512), dim3(256), 0, stream>>>(Qb, Kb, VbT, Ob);
  gemm_out<<<dim3(512), dim3(256), 0, stream>>>(Ob, WoT, out);
}

// Round 7
// 374.775 us; speedup vs baseline: 1.3645x; 1.0939x over previous
//
#include <hip/hip_runtime.h>
#include <hip/hip_bf16.h>

// MQA: B=2, S=2048, H=2048, NH=16, D=128
#define NB 2
#define NS 2048
#define NHID 2048
#define NHEAD 16
#define ND 128
#define NM (NB*NS)   // 4096

typedef __attribute__((ext_vector_type(8))) short s16x8;
typedef __attribute__((ext_vector_type(4))) float f32x4;
typedef unsigned long long ull;

__device__ __forceinline__ short f2bf(float x) {
  unsigned u = __float_as_uint(x);
  u = (u + 0x7fffu + ((u >> 16) & 1u)) >> 16;
  return (short)u;
}

__device__ __forceinline__ float fexp2(float x) {
  float r; asm("v_exp_f32 %0, %1" : "=v"(r) : "v"(x)); return r;
}
__device__ __forceinline__ unsigned cvtpk(float lo, float hi) {
  unsigned r; asm("v_cvt_pk_bf16_f32 %0, %1, %2" : "=v"(r) : "v"(lo), "v"(hi)); return r;
}

__device__ __forceinline__ int colmap(int wc, int ni) {
  return (ni < 2) ? (wc*32 + ni*16) : (64 + wc*32 + (ni-2)*16);
}

__device__ __forceinline__ void gload16(const short* g, short* l) {
  __builtin_amdgcn_global_load_lds(
      (const __attribute__((address_space(1))) void*)g,
      (__attribute__((address_space(3))) void*)l, 16, 0, 0);
}

// ---------------- conversions ----------------
__global__ __launch_bounds__(256) void cvt_f32_bf16(const float* __restrict__ src,
                                                    short* __restrict__ dst, int n4) {
  int i = blockIdx.x*256 + threadIdx.x;
  if (i >= n4) return;
  const float4 v = reinterpret_cast<const float4*>(src)[i];
  ull pk =
      (ull)(unsigned)cvtpk(v.x, v.y)
    | ((ull)(unsigned)cvtpk(v.z, v.w) << 32);
  reinterpret_cast<ull*>(dst)[i] = pk;
}

// src [K][N] fp32 -> dst [N][K] bf16
__global__ __launch_bounds__(256) void cvtT(const float* __restrict__ src,
                                            short* __restrict__ dst, int K, int N) {
  __shared__ float t[32][33];
  const int n0 = blockIdx.x*32, k0 = blockIdx.y*32;
  const int tx = threadIdx.x & 31, ty = threadIdx.x >> 5;
  #pragma unroll
  for (int i = 0; i < 4; ++i)
    t[ty + 8*i][tx] = src[(size_t)(k0 + ty + 8*i)*N + n0 + tx];
  __syncthreads();
  #pragma unroll
  for (int i = 0; i < 4; ++i)
    dst[(size_t)(n0 + ty + 8*i)*K + k0 + tx] = f2bf(t[tx][ty + 8*i]);
}

// Vb [4096][128] bf16 -> VbT [128][4096] bf16, XOR-swizzled: col s ^= (d&7)<<3
__global__ __launch_bounds__(256) void trans_v(const short* __restrict__ src,
                                               short* __restrict__ dst) {
  __shared__ short t[32][40];
  const int c0 = blockIdx.x*32;   // d
  const int r0 = blockIdx.y*32;   // mrow (s)
  const int tx = threadIdx.x & 31, ty = threadIdx.x >> 5;
  #pragma unroll
  for (int i = 0; i < 4; ++i)
    t[ty + 8*i][tx] = src[(size_t)(r0 + ty + 8*i)*128 + c0 + tx];
  __syncthreads();
  #pragma unroll
  for (int i = 0; i < 4; ++i) {
    const int d = c0 + ty + 8*i;
    dst[(size_t)d*4096 + ((r0 + tx) ^ ((d & 7) << 3))] = t[tx][ty + 8*i];
  }
}

// ---------------- GEMM1: QKV projection + RoPE epilogue ----------------
// flat grid 576, m-major XCD chunking; BK=64, XOR-swizzled LDS (pre-swizzled source)
// K rows written XOR-swizzled for attn: d ^= (s&7)<<3
__global__ __launch_bounds__(256) void gemm_qkv(
    const short* __restrict__ hsb, const short* __restrict__ WqT,
    const short* __restrict__ WkT, const short* __restrict__ WvT,
    const float* __restrict__ ropeC, const float* __restrict__ ropeS,
    short* __restrict__ Qb, short* __restrict__ Kb, short* __restrict__ Vb)
{
  const int tid = threadIdx.x;
  const int lane = tid & 63, wid = tid >> 6;
  const int wr = wid >> 1, wc = wid & 1;
  const int l15 = lane & 15, l4 = lane >> 4;
  const int bid = blockIdx.x;
  const int wg = (bid & 7) * 72 + (bid >> 3);   // 576 = 8*72, bijective
  const int m0 = (wg / 18) * 128;               // m-major: XCD gets 4 m-blocks x all ny
  const int ny = wg % 18;
  const short* Bt = (ny < 16) ? (WqT + (size_t)ny*128*2048) : (ny == 16 ? WkT : WvT);

  __shared__ short Al[128][64];   // 16 KB, BK=64
  __shared__ short Bl[128][64];   // 16 KB

  f32x4 acc[4][4];
  const f32x4 zf = {0.f,0.f,0.f,0.f};
  #pragma unroll
  for (int i=0;i<4;++i)
    #pragma unroll
    for (int j=0;j<4;++j) acc[i][j] = zf;

  const int sw7 = l15 & 7;

  for (int kt = 0; kt < 32; ++kt) {
    const int k0 = kt * 64;
    __syncthreads();
    #pragma unroll
    for (int rep=0; rep<4; ++rep) {
      const int idx = rep*256 + tid;          // 1024 16B-blocks per matrix
      const int row = idx >> 3;
      const int qs  = (idx & 7) ^ (row & 7);  // inverse-swizzled source block
      gload16(hsb + (size_t)(m0+row)*2048 + k0 + qs*8, &Al[0][0] + idx*8);
      gload16(Bt  + (size_t)row*2048      + k0 + qs*8, &Bl[0][0] + idx*8);
    }
    __syncthreads();
    #pragma unroll
    for (int kk=0; kk<2; ++kk) {
      s16x8 af[4], bfr[4];
      #pragma unroll
      for (int mi=0; mi<4; ++mi)
        af[mi] = *(const s16x8*)&Al[0][0 + (wr*64 + mi*16 + l15)*64 + (((kk*4 + l4) ^ sw7) * 8)];
      #pragma unroll
      for (int ni=0; ni<4; ++ni)
        bfr[ni] = *(const s16x8*)&Bl[0][0 + (colmap(wc,ni) + l15)*64 + (((kk*4 + l4) ^ sw7) * 8)];
      #pragma unroll
      for (int mi=0; mi<4; ++mi)
        #pragma unroll
        for (int ni=0; ni<4; ++ni)
          acc[mi][ni] = __builtin_amdgcn_mfma_f32_16x16x32_bf16(af[mi], bfr[ni], acc[mi][ni], 0,0,0);
    }
  }

  const bool isQ = (ny < 16), isK = (ny == 16);
  #pragma unroll
  for (int mi=0; mi<4; ++mi) {
    #pragma unroll
    for (int r=0; r<4; ++r) {
      const int mrow = m0 + wr*64 + mi*16 + l4*4 + r;
      const int s = mrow & 2047;
      const int bb = mrow >> 11;
      if (!isQ && !isK) {
        #pragma unroll
        for (int ni=0; ni<4; ++ni) {
          const int d = colmap(wc,ni) + l15;
          Vb[(size_t)mrow*128 + d] = f2bf(acc[mi][ni][r]);
        }
      } else {
        #pragma unroll
        for (int ni=0; ni<2; ++ni) {
          const int d = colmap(wc,ni) + l15;      // [0,64)
          const float c0 = ropeC[s*128 + d],      s0 = ropeS[s*128 + d];
          const float c1 = ropeC[s*128 + d + 64], s1 = ropeS[s*128 + d + 64];
          const float x0 = acc[mi][ni][r], x1 = acc[mi][ni+2][r];
          const float y0 = x0*c0 - x1*s0;
          const float y1 = x1*c1 + x0*s1;
          if (isK) {
            const int dsw = d ^ ((s & 7) << 3);   // swizzled column (stays in [0,64))
            Kb[(size_t)mrow*128 + dsw]      = f2bf(y0);
            Kb[(size_t)mrow*128 + dsw + 64] = f2bf(y1);
          } else {
            const size_t base = ((size_t)(bb*16 + ny)*2048 + s)*128;
            Qb[base + d]      = f2bf(y0);
            Qb[base + d + 64] = f2bf(y1);
          }
        }
      }
    }
  }
}

// ---------------- flash attention: staged, dbuf, swapped-QK^T softmax ----------------
__device__ __forceinline__ void qkt_pair(const short* KL, const s16x8 (&qfH)[4],
                                         const s16x8 (&qfL)[4], f32x4 (&scH)[4],
                                         f32x4 (&scL)[4], int l15, int l4, int sw) {
  __builtin_amdgcn_s_setprio(1);
  #pragma unroll
  for (int kk=0; kk<4; ++kk)
    #pragma unroll
    for (int n=0; n<4; ++n) {
      s16x8 kf = *(const s16x8*)&KL[(n*16 + l15)*128 + ((kk*32 + l4*8) ^ sw)];
      scH[n] = __builtin_amdgcn_mfma_f32_16x16x32_bf16(kf, qfH[kk], scH[n], 0,0,0);
      scL[n] = __builtin_amdgcn_mfma_f32_16x16x32_bf16(kf, qfL[kk], scL[n], 0,0,0);
    }
  __builtin_amdgcn_s_setprio(0);
}

__device__ __forceinline__ void qkt_one(const short* KL, const s16x8 (&qf)[4],
                                        f32x4 (&sc)[4], int l15, int l4, int sw) {
  __builtin_amdgcn_s_setprio(1);
  #pragma unroll
  for (int kk=0; kk<4; ++kk)
    #pragma unroll
    for (int n=0; n<4; ++n) {
      s16x8 kf = *(const s16x8*)&KL[(n*16 + l15)*128 + ((kk*32 + l4*8) ^ sw)];
      sc[n] = __builtin_amdgcn_mfma_f32_16x16x32_bf16(kf, qf[kk], sc[n], 0,0,0);
    }
  __builtin_amdgcn_s_setprio(0);
}

// softmax in S^T domain: lane's q = l15, in-lane kv = n*16 + l4*4 + r
// VALU-diet: raw v_exp, fma-folded arg, max3 tree, defer-max (THR=8), cvt_pk packing
__device__ __forceinline__ void sm16(f32x4 (&sc)[4], bool diag, int wid, int l15, int l4,
                                     int sw, float &m_run, float &l_run, f32x4 (&o)[8],
                                     short* Pl) {
  const float CEXP = 0.08838834764831845f * 1.44269504088896340f;
  float p[4][4];
  #pragma unroll
  for (int n=0;n<4;++n)
    #pragma unroll
    for (int r=0;r<4;++r) p[n][r] = sc[n][r];
  if (diag) {
    #pragma unroll
    for (int n=0;n<4;++n)
      #pragma unroll
      for (int r=0;r<4;++r)
        if (n*16 + l4*4 + r > wid*16 + l15) p[n][r] = -1e30f;
  }
  // max3-friendly tree
  float a0 = fmaxf(fmaxf(p[0][0], p[0][1]), p[0][2]);
  float a1 = fmaxf(fmaxf(p[0][3], p[1][0]), p[1][1]);
  float a2 = fmaxf(fmaxf(p[1][2], p[1][3]), p[2][0]);
  float a3 = fmaxf(fmaxf(p[2][1], p[2][2]), p[2][3]);
  float a4 = fmaxf(fmaxf(p[3][0], p[3][1]), p[3][2]);
  float b0 = fmaxf(fmaxf(a0, a1), a2);
  float b1 = fmaxf(fmaxf(a3, a4), p[3][3]);
  float pm = fmaxf(b0, b1);
  pm = fmaxf(pm, __shfl_xor(pm, 16));
  pm = fmaxf(pm, __shfl_xor(pm, 32));

  // defer-max: skip rescale while max drifts < 8 (P bounded by 2^(8*CEXP) ~ 2.03)
  if (!__all(pm <= m_run + 8.0f)) {
    const float mn = fmaxf(m_run, pm);
    const float al = fexp2((m_run - mn) * CEXP);
    m_run = mn;
    l_run *= al;
    #pragma unroll
    for (int r=0;r<4;++r) {
      const float a = __shfl(al, l4*4 + r);
      #pragma unroll
      for (int i=0;i<8;++i) o[i][r] *= a;
    }
  }
  const float mC = m_run * CEXP;
  #pragma unroll
  for (int n=0;n<4;++n)
    #pragma unroll
    for (int r=0;r<4;++r)
      p[n][r] = fexp2(__builtin_fmaf(p[n][r], CEXP, -mC));
  // pack + write P early; ds latency hides under the row-sum below
  #pragma unroll
  for (int n=0;n<4;++n) {
    ull w = (ull)(unsigned)cvtpk(p[n][0], p[n][1])
          | ((ull)(unsigned)cvtpk(p[n][2], p[n][3]) << 32);
    *(ull*)&Pl[l15*64 + ((n*16 + l4*4) ^ sw)] = w;
  }
  float rs = 0.f;
  #pragma unroll
  for (int n=0;n<4;++n)
    #pragma unroll
    for (int r=0;r<4;++r) rs += p[n][r];
  rs += __shfl_xor(rs, 16);
  rs += __shfl_xor(rs, 32);
  l_run += rs;
}

__device__ __forceinline__ void pv_pair(const short* VL, const s16x8 (&paH)[2],
                                        const s16x8 (&paL)[2], f32x4 (&oH)[8],
                                        f32x4 (&oL)[8], int l15, int l4, int sw) {
  __builtin_amdgcn_s_setprio(1);
  #pragma unroll
  for (int kb=0; kb<2; ++kb)
    #pragma unroll
    for (int d8=0; d8<8; ++d8) {
      s16x8 vf = *(const s16x8*)&VL[(d8*16 + l15)*64 + ((kb*32 + l4*8) ^ sw)];
      oH[d8] = __builtin_amdgcn_mfma_f32_16x16x32_bf16(paH[kb], vf, oH[d8], 0,0,0);
      oL[d8] = __builtin_amdgcn_mfma_f32_16x16x32_bf16(paL[kb], vf, oL[d8], 0,0,0);
    }
  __builtin_amdgcn_s_setprio(0);
}

__device__ __forceinline__ void pv_one(const short* VL, const s16x8 (&pa)[2],
                                       f32x4 (&o)[8], int l15, int l4, int sw) {
  __builtin_amdgcn_s_setprio(1);
  #pragma unroll
  for (int kb=0; kb<2; ++kb)
    #pragma unroll
    for (int d8=0; d8<8; ++d8) {
      s16x8 vf = *(const s16x8*)&VL[(d8*16 + l15)*64 + ((kb*32 + l4*8) ^ sw)];
      o[d8] = __builtin_amdgcn_mfma_f32_16x16x32_bf16(pa[kb], vf, o[d8], 0,0,0);
    }
  __builtin_amdgcn_s_setprio(0);
}

// grid flat 512: XCD-chunk swizzle; block owns q-tiles lo=pr, hi=31-pr (33 passes)
__global__ __launch_bounds__(256) void attn_fwd(
    const short* __restrict__ Qb, const short* __restrict__ Kb,
    const short* __restrict__ VbT, short* __restrict__ Ob)
{
  const int tid = threadIdx.x;
  const int lane = tid & 63, wid = tid >> 6;
  const int l15 = lane & 15, l4 = lane >> 4;
  const int bid = blockIdx.x;
  const int wg = (bid & 7)*64 + (bid >> 3);
  const int pr = wg & 15, h = (wg >> 4) & 15, b = wg >> 8;
  const int lo = pr, hi = 31 - pr;
  const int sw = (l15 & 7) << 3;

  __shared__ short Kl[2][64*128];   // 32 KB
  __shared__ short Vt[2][128*64];   // 32 KB
  __shared__ short Pb[4][2][16*64]; // 16 KB
  short* PlH = &Pb[wid][0][0];
  short* PlL = &Pb[wid][1][0];

  s16x8 qfH[4], qfL[4];
  {
    const short* QpL = Qb + ((size_t)(b*16 + h)*2048 + lo*64 + wid*16 + l15)*128 + l4*8;
    const short* QpH = Qb + ((size_t)(b*16 + h)*2048 + hi*64 + wid*16 + l15)*128 + l4*8;
    #pragma unroll
    for (int kk=0; kk<4; ++kk) { qfL[kk] = *(const s16x8*)(QpL + kk*32);
                                 qfH[kk] = *(const s16x8*)(QpH + kk*32); }
  }

  float mH = -1e30f, lH = 0.f, mL = -1e30f, lL = 0.f;
  f32x4 oH[8], oL[8];
  const f32x4 zf = {0.f,0.f,0.f,0.f};
  #pragma unroll
  for (int i=0;i<8;++i){ oH[i]=zf; oL[i]=zf; }

  const short* Kg = Kb + (size_t)b*2048*128;
  const short* Vg = VbT + (size_t)b*2048;

  #define STAGE(bufi, tt) do {                                              \
    const int kv0_ = (tt)*64;                                               \
    _Pragma("unroll")                                                       \
    for (int rep=0; rep<4; ++rep) {                                         \
      const int c = tid + rep*256;                                          \
      gload16(Kg + (size_t)(kv0_ + (c>>4))*128 + (c&15)*8, &Kl[bufi][c*8]); \
    }                                                                       \
    _Pragma("unroll")                                                       \
    for (int rep=0; rep<4; ++rep) {                                         \
      const int c = tid + rep*256;                                          \
      gload16(Vg + (size_t)(c>>3)*4096 + kv0_ + (c&7)*8, &Vt[bufi][c*8]);   \
    }                                                                       \
  } while(0)

  STAGE(0, 0);
  __syncthreads();
  int buf = 0;
  int t = 0;

  // paired phase: t <= lo  (lo < hi always since lo<=15<16<=hi)
  for (; t <= lo; ++t) {
    STAGE(buf^1, t+1);
    const short* KL = &Kl[buf][0];
    const short* VL = &Vt[buf][0];
    f32x4 scH[4], scL[4];
    #pragma unroll
    for (int n=0;n<4;++n){ scH[n]=zf; scL[n]=zf; }
    qkt_pair(KL, qfH, qfL, scH, scL, l15, l4, sw);
    sm16(scH, false, wid, l15, l4, sw, mH, lH, oH, PlH);
    sm16(scL, (t == lo), wid, l15, l4, sw, mL, lL, oL, PlL);
    s16x8 paH[2], paL[2];
    #pragma unroll
    for (int kb=0; kb<2; ++kb) {
      paH[kb] = *(const s16x8*)&PlH[l15*64 + ((kb*32 + l4*8) ^ sw)];
      paL[kb] = *(const s16x8*)&PlL[l15*64 + ((kb*32 + l4*8) ^ sw)];
    }
    pv_pair(VL, paH, paL, oH, oL, l15, l4, sw);
    __syncthreads();
    buf ^= 1;
  }
  // H-only phase
  for (; t <= hi; ++t) {
    if (t < hi) STAGE(buf^1, t+1);
    const short* KL = &Kl[buf][0];
    const short* VL = &Vt[buf][0];
    f32x4 scH[4];
    #pragma unroll
    for (int n=0;n<4;++n) scH[n]=zf;
    qkt_one(KL, qfH, scH, l15, l4, sw);
    sm16(scH, (t == hi), wid, l15, l4, sw, mH, lH, oH, PlH);
    s16x8 paH[2];
    #pragma unroll
    for (int kb=0; kb<2; ++kb)
      paH[kb] = *(const s16x8*)&PlH[l15*64 + ((kb*32 + l4*8) ^ sw)];
    pv_one(VL, paH, oH, l15, l4, sw);
    __syncthreads();
    buf ^= 1;
  }
  #undef STAGE

  const float invH = 1.0f / lH;
  const float invL = 1.0f / lL;
  #pragma unroll
  for (int r=0;r<4;++r) {
    const float iH = __shfl(invH, l4*4 + r);
    const float iL = __shfl(invL, l4*4 + r);
    const size_t baseH = ((size_t)(b*2048) + hi*64 + wid*16 + l4*4 + r)*2048 + (size_t)h*128;
    const size_t baseL = ((size_t)(b*2048) + lo*64 + wid*16 + l4*4 + r)*2048 + (size_t)h*128;
    #pragma unroll
    for (int d8=0; d8<8; ++d8) {
      Ob[baseH + d8*16 + l15] = f2bf(oH[d8][r] * iH);
      Ob[baseL + d8*16 + l15] = f2bf(oL[d8][r] * iL);
    }
  }
}

// ---------------- GEMM2: O @ Wo -> fp32 out ----------------
// flat grid 512, m-major XCD chunking; BK=64, XOR-swizzled LDS
__global__ __launch_bounds__(256) void gemm_out(
    const short* __restrict__ Ob, const short* __restrict__ WoT,
    float* __restrict__ out)
{
  const int tid = threadIdx.x;
  const int lane = tid & 63, wid = tid >> 6;
  const int wr = wid >> 1, wc = wid & 1;
  const int l15 = lane & 15, l4 = lane >> 4;
  const int bid = blockIdx.x;
  const int wg = (bid & 7) * 64 + (bid >> 3);   // 512 = 8*64, bijective
  const int m0 = (wg >> 4) * 128;               // m-major: XCD gets 4 m-blocks x all n
  const int n0 = (wg & 15) * 128;

  __shared__ short Al[128][64];
  __shared__ short Bl[128][64];

  f32x4 acc[4][4];
  const f32x4 zf = {0.f,0.f,0.f,0.f};
  #pragma unroll
  for (int i=0;i<4;++i)
    #pragma unroll
    for (int j=0;j<4;++j) acc[i][j] = zf;

  const int sw7 = l15 & 7;

  for (int kt = 0; kt < 32; ++kt) {
    const int k0 = kt * 64;
    __syncthreads();
    #pragma unroll
    for (int rep=0; rep<4; ++rep) {
      const int idx = rep*256 + tid;
      const int row = idx >> 3;
      const int qs  = (idx & 7) ^ (row & 7);
      gload16(Ob  + (size_t)(m0+row)*2048 + k0 + qs*8, &Al[0][0] + idx*8);
      gload16(WoT + (size_t)(n0+row)*2048 + k0 + qs*8, &Bl[0][0] + idx*8);
    }
    __syncthreads();
    #pragma unroll
    for (int kk=0; kk<2; ++kk) {
      s16x8 af[4], bfr[4];
      #pragma unroll
      for (int mi=0; mi<4; ++mi)
        af[mi] = *(const s16x8*)&Al[0][0 + (wr*64 + mi*16 + l15)*64 + (((kk*4 + l4) ^ sw7) * 8)];
      #pragma unroll
      for (int ni=0; ni<4; ++ni)
        bfr[ni] = *(const s16x8*)&Bl[0][0 + (colmap(wc,ni) + l15)*64 + (((kk*4 + l4) ^ sw7) * 8)];
      #pragma unroll
      for (int mi=0; mi<4; ++mi)
        #pragma unroll
        for (int ni=0; ni<4; ++ni)
          acc[mi][ni] = __builtin_amdgcn_mfma_f32_16x16x32_bf16(af[mi], bfr[ni], acc[mi][ni], 0,0,0);
    }
  }

  #pragma unroll
  for (int mi=0; mi<4; ++mi)
    #pragma unroll
    for (int r=0; r<4; ++r) {
      const int mrow = m0 + wr*64 + mi*16 + l4*4 + r;
      #pragma unroll
      for (int ni=0; ni<4; ++ni)
        out[(size_t)mrow*2048 + n0 + colmap(wc,ni) + l15] = acc[mi][ni][r];
    }
}

// ---------------- launch ----------------
extern "C" void kernel_launch(void* const* d_in, const int* in_sizes, int n_in,
                              void* d_out, int out_size, void* d_ws, size_t ws_size,
                              hipStream_t stream) {
  const float* hidden = (const float*)d_in[0];
  // d_in[1] attention_mask: exactly causal -> analytic
  const float* ropeC  = (const float*)d_in[2];
  const float* ropeS  = (const float*)d_in[3];
  const float* Wq     = (const float*)d_in[4];
  const float* Wk     = (const float*)d_in[5];
  const float* Wv     = (const float*)d_in[6];
  const float* Wo     = (const float*)d_in[7];
  float* out = (float*)d_out;
  char* ws = (char*)d_ws;

  short* hsb = (short*)(ws + 0);                 // 16,777,216
  short* WqT = (short*)(ws + 16777216);          //  8,388,608
  short* WkT = (short*)(ws + 25165824);          //    524,288
  short* WvT = (short*)(ws + 25690112);          //    524,288
  short* WoT = (short*)(ws + 26214400);          //  8,388,608
  short* Qb  = (short*)(ws + 34603008);          // 16,777,216
  short* Kb  = (short*)(ws + 51380224);          //  1,048,576
  short* Vb  = (short*)(ws + 52428800);          //  1,048,576
  short* VbT = (short*)(ws + 53477376);          //  1,048,576
  short* Ob  = hsb;                              // alias (hsb dead after gemm_qkv)

  cvt_f32_bf16<<<dim3((NM*NHID/4 + 255)/256), dim3(256), 0, stream>>>(hidden, hsb, NM*NHID/4);
  cvtT<<<dim3(64,64), dim3(256), 0, stream>>>(Wq, WqT, 2048, 2048);
  cvtT<<<dim3(4, 64), dim3(256), 0, stream>>>(Wk, WkT, 2048, 128);
  cvtT<<<dim3(4, 64), dim3(256), 0, stream>>>(Wv, WvT, 2048, 128);
  cvtT<<<dim3(64,64), dim3(256), 0, stream>>>(Wo, WoT, 2048, 2048);

  gemm_qkv<<<dim3(576), dim3(256), 0, stream>>>(hsb, WqT, WkT, WvT, ropeC, ropeS, Qb, Kb, Vb);
  trans_v<<<dim3(4, 128), dim3(256), 0, stream>>>(Vb, VbT);
  attn_fwd<<<dim3(512), dim3(256), 0, stream>>>(Qb, Kb, VbT, Ob);
  gemm_out<<<dim3(512), dim3(256), 0, stream>>>(Ob, WoT, out);
}